// Round 6
// baseline (384.913 us; speedup 1.0000x reference)
//
#include <hip/hip_runtime.h>
#include <math.h>

typedef __attribute__((ext_vector_type(8))) short bf16x8;
typedef __attribute__((ext_vector_type(4))) float f32x4;

#define CSR_P 256

// ---------------- bf16 helpers ----------------
__device__ __forceinline__ unsigned short f2bf(float f){
  union { float f; unsigned int u; } c; c.f = f;
  unsigned int u = c.u;
  u += 0x7fff + ((u >> 16) & 1);          // RNE
  return (unsigned short)(u >> 16);
}
__device__ __forceinline__ float bf2f(unsigned short h){
  union { unsigned int u; float f; } c; c.u = ((unsigned int)h) << 16;
  return c.f;
}

// ---------------- wave helpers ----------------
__device__ __forceinline__ float wsum64(float v){
  #pragma unroll
  for (int off = 32; off > 0; off >>= 1) v += __shfl_xor(v, off, 64);
  return v;
}

// ---------------- merged weight-prep + bucket histogram ----------------
__global__ __launch_bounds__(256) void prephist_kernel(
    const int* __restrict__ tgt0, int NB0, const int* __restrict__ tgt1, int NB1, int E,
    int* __restrict__ counts0, int* __restrict__ counts1,
    const float* __restrict__ K0, const float* __restrict__ Q0, const float* __restrict__ V0,
    const float* __restrict__ W10, const float* __restrict__ W20,
    const float* __restrict__ K1, const float* __restrict__ Q1, const float* __restrict__ V1,
    const float* __restrict__ W11, const float* __restrict__ W21,
    unsigned short* __restrict__ btV0, unsigned short* __restrict__ btkq0,
    unsigned short* __restrict__ btW10, unsigned short* __restrict__ btW20,
    unsigned short* __restrict__ btV1, unsigned short* __restrict__ btkq1,
    unsigned short* __restrict__ btW11, unsigned short* __restrict__ btW21,
    int* __restrict__ cursors){
  if (blockIdx.x >= CSR_P){
    int pb = blockIdx.x - CSR_P;
    if (pb == 0 && blockIdx.y == 0 && threadIdx.x == 0){ cursors[0] = 0; cursors[1] = 0; }
    const float *K, *Q, *V, *W1, *W2;
    unsigned short *btV, *btkq, *btW1, *btW2;
    if (blockIdx.y == 0){ K=K0; Q=Q0; V=V0; W1=W10; W2=W20; btV=btV0; btkq=btkq0; btW1=btW10; btW2=btW20; }
    else                { K=K1; Q=Q1; V=V1; W1=W11; W2=W21; btV=btV1; btkq=btkq1; btW1=btW11; btW2=btW21; }
    int i = pb * 256 + threadIdx.x;
    if (i < 512){
      int h = i >> 7, c = i & 127;
      const float* Kp = K + (size_t)h * 4096 + (size_t)c * 32;
      const float* Qp = Q + h * 32;
      float s = 0.f;
      #pragma unroll
      for (int d = 0; d < 32; ++d) s += Kp[d] * Qp[d];
      unsigned short hi = f2bf(s);
      btkq[h * 128 + c]       = hi;
      btkq[(4 + h) * 128 + c] = f2bf(s - bf2f(hi));
      return;
    }
    int j = i - 512;
    if (j < 16384){
      int n = j >> 7, k = j & 127;
      int h = n >> 5, d = n & 31;
      btV[j] = f2bf(V[(size_t)h * 4096 + (size_t)k * 32 + d]);
      return;
    }
    j -= 16384;
    if (j < 16384){
      int n = j >> 7, k = j & 127;
      btW1[j] = f2bf(W1[(size_t)k * 128 + n]);
      return;
    }
    j -= 16384;
    if (j < 16384){
      int n = j >> 7, k = j & 127;
      btW2[j] = f2bf(W2[(size_t)k * 128 + n]);
    }
    return;
  }
  // histogram role
  const int* tgt; int NB; int* counts;
  if (blockIdx.y == 0){ tgt = tgt0; NB = NB0; counts = counts0; }
  else                { tgt = tgt1; NB = NB1; counts = counts1; }
  __shared__ int hist[256];
  for (int i = threadIdx.x; i < NB; i += 256) hist[i] = 0;
  __syncthreads();
  int chunk = (E + CSR_P - 1) / CSR_P;
  int b0 = blockIdx.x * chunk, b1 = min(b0 + chunk, E);
  for (int e = b0 + threadIdx.x; e < b1; e += 256)
    atomicAdd(&hist[tgt[e] >> 8], 1);
  __syncthreads();
  for (int i = threadIdx.x; i < NB; i += 256)
    counts[i * CSR_P + blockIdx.x] = hist[i];
}

// Per-bucket scan over its 256 chunk-counts; bucket base assigned via atomic cursor.
__global__ __launch_bounds__(256) void bscan_kernel(const int* __restrict__ counts0, int NB0,
                                                    const int* __restrict__ counts1,
                                                    int* __restrict__ blkoff0, int* __restrict__ blkoff1,
                                                    int* __restrict__ btot0, int* __restrict__ btot1,
                                                    int* __restrict__ base0, int* __restrict__ base1,
                                                    int* __restrict__ cursors){
  int i = blockIdx.x;
  const int* counts; int* blkoff; int* btot; int* bbase; int* cur; int b;
  if (i < NB0){ counts = counts0; blkoff = blkoff0; btot = btot0; bbase = base0; cur = &cursors[0]; b = i; }
  else        { counts = counts1; blkoff = blkoff1; btot = btot1; bbase = base1; cur = &cursors[1]; b = i - NB0; }
  __shared__ int wtmp[5];
  int tid = threadIdx.x, lane = tid & 63, wv = tid >> 6;
  int c = counts[b * CSR_P + tid];
  int s = c;
  #pragma unroll
  for (int off = 1; off < 64; off <<= 1){
    int t = __shfl_up(s, off, 64);
    if (lane >= off) s += t;
  }
  if (lane == 63) wtmp[wv] = s;
  __syncthreads();
  if (tid == 0){
    int a0 = wtmp[0], a1 = wtmp[1], a2 = wtmp[2], a3 = wtmp[3];
    wtmp[0] = 0; wtmp[1] = a0; wtmp[2] = a0 + a1; wtmp[3] = a0 + a1 + a2;
    int total = a0 + a1 + a2 + a3;
    wtmp[4] = total;
    btot[b] = total;
    int padded = ((total + 3) & ~3) + 1024;      // room for per-row x4 padding
    bbase[b] = atomicAdd(cur, padded);           // 4-aligned (padded is x4)
  }
  __syncthreads();
  blkoff[b * CSR_P + tid] = s - c + wtmp[wv];
}

__global__ __launch_bounds__(256) void scatter2_kernel(
    const int* __restrict__ tgt0, const int* __restrict__ src0, int NB0,
    const int* __restrict__ base0, const int* __restrict__ blkoff0, int* __restrict__ pairs0,
    const int* __restrict__ tgt1, const int* __restrict__ src1, int NB1,
    const int* __restrict__ base1, const int* __restrict__ blkoff1, int* __restrict__ pairs1,
    int E){
  const int *tgt, *src, *bbase, *boff; int NB; int* pairs;
  if (blockIdx.y == 0){ tgt=tgt0; src=src0; bbase=base0; boff=blkoff0; NB=NB0; pairs=pairs0; }
  else                { tgt=tgt1; src=src1; bbase=base1; boff=blkoff1; NB=NB1; pairs=pairs1; }
  __shared__ int cur[256];
  for (int i = threadIdx.x; i < NB; i += 256)
    cur[i] = bbase[i] + boff[i * CSR_P + blockIdx.x];
  __syncthreads();
  int chunk = (E + CSR_P - 1) / CSR_P;
  int b0 = blockIdx.x * chunk, b1 = min(b0 + chunk, E);
  for (int e = b0 + threadIdx.x; e < b1; e += 256){
    int t = tgt[e];
    int pos = atomicAdd(&cur[t >> 8], 1);
    pairs[pos] = ((t & 255) << 24) | src[e];     // src < 2^24
  }
}

// Within each 256-target bucket: counting-scatter keyed by (tgt, src>>13) so each
// row's cols come out sorted by source tile.
__global__ __launch_bounds__(1024) void build2_kernel(
    const int* __restrict__ base0, const int* __restrict__ btot0, int NB0,
    const int* __restrict__ pairs0, int n0, int d0,
    int* __restrict__ rp0, int* __restrict__ kc0, int* __restrict__ col0,
    const int* __restrict__ base1, const int* __restrict__ btot1, int NB1,
    const int* __restrict__ pairs1, int n1, int d1,
    int* __restrict__ rp1, int* __restrict__ kc1, int* __restrict__ col1){
  int b = blockIdx.x;
  const int *bbase, *bt; const int* pairs; int n_tgt, dummy;
  int *rowptr, *kcnt, *col;
  if (blockIdx.y == 0){
    if (b >= NB0) return;
    bbase=base0; bt=btot0; pairs=pairs0; n_tgt=n0; dummy=d0; rowptr=rp0; kcnt=kc0; col=col0;
  } else {
    if (b >= NB1) return;
    bbase=base1; bt=btot1; pairs=pairs1; n_tgt=n1; dummy=d1; rowptr=rp1; kcnt=kc1; col=col1;
  }
  __shared__ int hist2[2048];   // per-(tgt, tile) counts, tile = src >> 13
  __shared__ int cur2[2048];    // running scatter cursors per (tgt, tile)
  __shared__ int hist[256];     // per-tgt totals
  __shared__ int excl[256];     // per-tgt exclusive (padded) offsets
  int tid = threadIdx.x;
  int start = bbase[b];              // 4-aligned by construction
  int end   = start + bt[b];
  for (int i = tid; i < 2048; i += 1024) hist2[i] = 0;
  __syncthreads();
  for (int e = start + tid; e < end; e += 1024){
    int p = pairs[e];
    atomicAdd(&hist2[(((p >> 24) & 255) << 3) | ((p & 0xFFFFFF) >> 13)], 1);
  }
  __syncthreads();
  if (tid < 256){
    int run = 0;
    #pragma unroll
    for (int t = 0; t < 8; ++t){ cur2[tid * 8 + t] = run; run += hist2[tid * 8 + t]; }
    hist[tid] = run;
  }
  __syncthreads();
  if (tid < 64){
    int lane = tid;
    int p0 = (hist[4 * lane]     + 3) & ~3;
    int p1 = (hist[4 * lane + 1] + 3) & ~3;
    int p2 = (hist[4 * lane + 2] + 3) & ~3;
    int p3 = (hist[4 * lane + 3] + 3) & ~3;
    int tsum = p0 + p1 + p2 + p3;
    int s = tsum;
    #pragma unroll
    for (int off = 1; off < 64; off <<= 1){
      int t = __shfl_up(s, off, 64);
      if (lane >= off) s += t;
    }
    int e0 = s - tsum;
    excl[4 * lane]     = e0;
    excl[4 * lane + 1] = e0 + p0;
    excl[4 * lane + 2] = e0 + p0 + p1;
    excl[4 * lane + 3] = e0 + p0 + p1 + p2;
  }
  __syncthreads();
  int t0 = b << 8;
  int valid = min(256, n_tgt - t0);
  if (tid < 256){
    int e0 = excl[tid];
    #pragma unroll
    for (int t = 0; t < 8; ++t) cur2[tid * 8 + t] += e0;
  }
  for (int i = tid; i < valid; i += 1024){
    rowptr[t0 + i] = start + excl[i];
    kcnt[t0 + i]   = (hist[i] + 3) & ~3;
  }
  __syncthreads();
  for (int e = start + tid; e < end; e += 1024){
    int p = pairs[e];
    int s = p & 0xFFFFFF;
    int pos = atomicAdd(&cur2[(((p >> 24) & 255) << 3) | (s >> 13)], 1);
    col[start + pos] = s;
  }
  __syncthreads();
  for (int i = tid; i < valid; i += 1024){
    int hc = hist[i], pc = (hc + 3) & ~3;
    int base = start + excl[i];
    for (int j = hc; j < pc; ++j) col[base + j] = dummy;
  }
}

// ---------------- fused xV + logits GEMM ----------------
__global__ __launch_bounds__(256) void gemm_xvl(const float* __restrict__ x,
                                                const unsigned short* __restrict__ btV,
                                                const unsigned short* __restrict__ btkq,
                                                unsigned short* __restrict__ xv,
                                                float* __restrict__ expl, int R){
  __shared__ unsigned short As[64 * 136];
  __shared__ unsigned short Bs[144 * 136];   // rows 136..143 uninit: pollute only unused cols
  int tid = threadIdx.x;
  int row0 = blockIdx.x * 64;

  #pragma unroll
  for (int i = 0; i < 16; ++i){
    int f = tid + i * 256;
    int n = f >> 5, c4 = f & 31;
    *(ushort4*)&Bs[n * 136 + c4 * 4] = *(const ushort4*)(btV + n * 128 + c4 * 4);
  }
  {
    int n = tid >> 5, c4 = tid & 31;       // 256 ushort4 = rows 128..135
    *(ushort4*)&Bs[(128 + n) * 136 + c4 * 4] = *(const ushort4*)(btkq + n * 128 + c4 * 4);
  }
  #pragma unroll
  for (int i = 0; i < 8; ++i){
    int f = tid + i * 256;
    int r = f >> 5, c4 = f & 31;
    float4 v = make_float4(0.f, 0.f, 0.f, 0.f);
    if (row0 + r < R) v = *(const float4*)(x + (size_t)(row0 + r) * 128 + c4 * 4);
    ushort4 h;
    h.x = f2bf(v.x); h.y = f2bf(v.y); h.z = f2bf(v.z); h.w = f2bf(v.w);
    *(ushort4*)&As[r * 136 + c4 * 4] = h;
  }
  __syncthreads();

  int lane = tid & 63, wv = tid >> 6;
  int m = lane & 15, quad = lane >> 4;
  f32x4 acc[9];
  #pragma unroll
  for (int j = 0; j < 9; ++j) acc[j] = (f32x4){0.f, 0.f, 0.f, 0.f};

  #pragma unroll
  for (int q = 0; q < 4; ++q){
    bf16x8 a = *(const bf16x8*)&As[(wv * 16 + m) * 136 + q * 32 + quad * 8];
    #pragma unroll
    for (int j = 0; j < 9; ++j){
      bf16x8 b = *(const bf16x8*)&Bs[(j * 16 + m) * 136 + q * 32 + quad * 8];
      acc[j] = __builtin_amdgcn_mfma_f32_16x16x32_bf16(a, b, acc[j], 0, 0, 0);
    }
  }

  #pragma unroll
  for (int j = 0; j < 8; ++j){
    int colc = j * 16 + m;
    #pragma unroll
    for (int r = 0; r < 4; ++r){
      int gr = row0 + wv * 16 + quad * 4 + r;
      if (gr <= R) xv[(size_t)gr * 128 + colc] = f2bf(acc[j][r]);   // row R: acc==0
    }
  }
  #pragma unroll
  for (int r = 0; r < 4; ++r){
    int gr = row0 + wv * 16 + quad * 4 + r;
    float lg = acc[8][r] + __shfl_xor(acc[8][r], 4, 64);   // hi + lo (lanes m<4 valid)
    if (m < 4 && gr <= R)
      expl[(size_t)gr * 4 + m] = (gr == R) ? 0.f : __expf(lg);
  }
}

// ---------------- softmax-aggregate + (+Qw) + LN0 : one wave per target ----------------
__global__ __launch_bounds__(256) void agg_kernel(const int* __restrict__ rowptr,
                                                  const int* __restrict__ kcnt,
                                                  const int* __restrict__ col,
                                                  const float* __restrict__ expl,
                                                  const unsigned short* __restrict__ xV,
                                                  const float* __restrict__ qvec,
                                                  const float* __restrict__ g0,
                                                  const float* __restrict__ b0,
                                                  unsigned short* __restrict__ hb_out,
                                                  int n_tgt){
  int wv_id = __builtin_amdgcn_readfirstlane(threadIdx.x >> 6);
  int wid = (blockIdx.x << 2) + wv_id;
  if (wid >= n_tgt) return;
  int lane = threadIdx.x & 63;
  int half = lane >> 5;                 // which edge of the pair this lane serves
  int c    = lane & 31;                 // channel block: channels 4c .. 4c+3
  unsigned hh = (unsigned)(c >> 3);     // head of this channel block
  int beg = rowptr[wid];          // scalar load
  int k   = kcnt[wid];            // scalar load

  const uint2* xv64 = (const uint2*)xV;
  float acc0 = 0.f, acc1 = 0.f, acc2 = 0.f, acc3 = 0.f, sumw = 0.f;
  #pragma unroll 2
  for (int e = 0; e < k; e += 4){
    int4 cc = *(const int4*)(col + beg + e);      // s_load_dwordx4 (uniform address)
    #pragma unroll
    for (int p = 0; p < 2; ++p){
      int sA = p ? cc.z : cc.x;
      int sB = p ? cc.w : cc.y;
      int se = half ? sB : sA;                    // per-lane select (v_cndmask)
      float a  = expl[((unsigned)se << 2) + hh];  // 1 dword / edge-pair-half
      uint2 v  = xv64[((unsigned)se << 5) + (unsigned)c];  // 8B: 4 channels
      union { unsigned u; float f; } t0, t1, t2, t3;
      t0.u = v.x << 16;          t1.u = v.x & 0xffff0000u;
      t2.u = v.y << 16;          t3.u = v.y & 0xffff0000u;
      sumw += a;
      acc0 += a * t0.f;  acc1 += a * t1.f;
      acc2 += a * t2.f;  acc3 += a * t3.f;
    }
  }
  // fold the two halves (each processed every other edge)
  sumw += __shfl_xor(sumw, 32, 64);
  acc0 += __shfl_xor(acc0, 32, 64);
  acc1 += __shfl_xor(acc1, 32, 64);
  acc2 += __shfl_xor(acc2, 32, 64);
  acc3 += __shfl_xor(acc3, 32, 64);

  float inv = (sumw > 0.f) ? 1.f / sumw : 0.f;
  acc0 *= inv; acc1 *= inv; acc2 *= inv; acc3 *= inv;

  float4 q4 = *(const float4*)(qvec + 4 * c);
  acc0 += q4.x; acc1 += q4.y; acc2 += q4.z; acc3 += q4.w;

  // every channel is present in both halves -> divide by 256, not 128
  float mean = wsum64(acc0 + acc1 + acc2 + acc3) * (1.f / 256.f);
  float d0 = acc0 - mean, d1 = acc1 - mean, d2 = acc2 - mean, d3 = acc3 - mean;
  float var = wsum64(d0 * d0 + d1 * d1 + d2 * d2 + d3 * d3) * (1.f / 256.f);
  float rstd = rsqrtf(var + 1e-5f);
  float4 g4 = *(const float4*)(g0 + 4 * c);
  float4 b4 = *(const float4*)(b0 + 4 * c);
  float o0 = d0 * rstd * g4.x + b4.x;
  float o1 = d1 * rstd * g4.y + b4.y;
  float o2 = d2 * rstd * g4.z + b4.z;
  float o3 = d3 * rstd * g4.w + b4.w;
  if (half == 0){
    uint2 pk;
    pk.x = ((unsigned)f2bf(o1) << 16) | (unsigned)f2bf(o0);
    pk.y = ((unsigned)f2bf(o3) << 16) | (unsigned)f2bf(o2);
    *(uint2*)(hb_out + 128 * (size_t)wid + 4 * c) = pk;
  }
}

// ---------------- fused MLP + LN1: out = relu(LN(A + relu(relu(A@W1)@W2))) ------------
__global__ __launch_bounds__(256) void mfma_mlp_ln(const unsigned short* __restrict__ A,
                                                   const unsigned short* __restrict__ Bt1,
                                                   const unsigned short* __restrict__ Bt2,
                                                   const float* __restrict__ g,
                                                   const float* __restrict__ b,
                                                   float* __restrict__ outp, int R){
  __shared__ unsigned short As[64 * 136];
  __shared__ unsigned short Bs[128 * 136];
  int tid = threadIdx.x;
  int row0 = blockIdx.x * 64;

  #pragma unroll
  for (int i = 0; i < 16; ++i){
    int f = tid + i * 256;
    int n = f >> 5, c4 = f & 31;
    *(ushort4*)&Bs[n * 136 + c4 * 4] = *(const ushort4*)(Bt1 + n * 128 + c4 * 4);
  }
  #pragma unroll
  for (int i = 0; i < 8; ++i){
    int f = tid + i * 256;
    int r = f >> 5, c4 = f & 31;
    ushort4 v = make_ushort4(0, 0, 0, 0);
    if (row0 + r < R) v = *(const ushort4*)(A + (size_t)(row0 + r) * 128 + c4 * 4);
    *(ushort4*)&As[r * 136 + c4 * 4] = v;
  }
  __syncthreads();

  int lane = tid & 63, wv = tid >> 6;
  int m = lane & 15, quad = lane >> 4;
  f32x4 acc[8];
  #pragma unroll
  for (int j = 0; j < 8; ++j) acc[j] = (f32x4){0.f, 0.f, 0.f, 0.f};

  // t = relu(A @ W1)
  #pragma unroll
  for (int q = 0; q < 4; ++q){
    bf16x8 a = *(const bf16x8*)&As[(wv * 16 + m) * 136 + q * 32 + quad * 8];
    #pragma unroll
    for (int j = 0; j < 8; ++j){
      bf16x8 b8 = *(const bf16x8*)&Bs[(j * 16 + m) * 136 + q * 32 + quad * 8];
      acc[j] = __builtin_amdgcn_mfma_f32_16x16x32_bf16(a, b8, acc[j], 0, 0, 0);
    }
  }

  // pre-read residual before overwrite
  float res[4][8];
  #pragma unroll
  for (int r = 0; r < 4; ++r)
    #pragma unroll
    for (int j = 0; j < 8; ++j)
      res[r][j] = bf2f(As[(wv * 16 + quad * 4 + r) * 136 + j * 16 + m]);
  __syncthreads();

  // t -> As (bf16), W2^T -> Bs
  #pragma unroll
  for (int j = 0; j < 8; ++j){
    #pragma unroll
    for (int r = 0; r < 4; ++r)
      As[(wv * 16 + quad * 4 + r) * 136 + j * 16 + m] = f2bf(fmaxf(acc[j][r], 0.f));
  }
  #pragma unroll
  for (int i = 0; i < 16; ++i){
    int f = tid + i * 256;
    int n = f >> 5, c4 = f & 31;
    *(ushort4*)&Bs[n * 136 + c4 * 4] = *(const ushort4*)(Bt2 + n * 128 + c4 * 4);
  }
  __syncthreads();

  // m2 = t @ W2
  #pragma unroll
  for (int j = 0; j < 8; ++j) acc[j] = (f32x4){0.f, 0.f, 0.f, 0.f};
  #pragma unroll
  for (int q = 0; q < 4; ++q){
    bf16x8 a = *(const bf16x8*)&As[(wv * 16 + m) * 136 + q * 32 + quad * 8];
    #pragma unroll
    for (int j = 0; j < 8; ++j){
      bf16x8 b8 = *(const bf16x8*)&Bs[(j * 16 + m) * 136 + q * 32 + quad * 8];
      acc[j] = __builtin_amdgcn_mfma_f32_16x16x32_bf16(a, b8, acc[j], 0, 0, 0);
    }
  }

  float gv[8], bv[8];
  #pragma unroll
  for (int j = 0; j < 8; ++j){ gv[j] = g[j * 16 + m]; bv[j] = b[j * 16 + m]; }

  #pragma unroll
  for (int r = 0; r < 4; ++r){
    int gr = row0 + wv * 16 + quad * 4 + r;
    if (gr >= R) continue;
    float v[8];
    float s = 0.f;
    #pragma unroll
    for (int j = 0; j < 8; ++j){
      float mm = fmaxf(acc[j][r], 0.f);
      v[j] = res[r][j] + mm;
      s += v[j];
    }
    s += __shfl_xor(s, 1, 64); s += __shfl_xor(s, 2, 64);
    s += __shfl_xor(s, 4, 64); s += __shfl_xor(s, 8, 64);
    float mean = s * (1.f / 128.f);
    float s2 = 0.f;
    #pragma unroll
    for (int j = 0; j < 8; ++j){ v[j] -= mean; s2 += v[j] * v[j]; }
    s2 += __shfl_xor(s2, 1, 64); s2 += __shfl_xor(s2, 2, 64);
    s2 += __shfl_xor(s2, 4, 64); s2 += __shfl_xor(s2, 8, 64);
    float rstd = rsqrtf(s2 * (1.f / 128.f) + 1e-5f);
    #pragma unroll
    for (int j = 0; j < 8; ++j)
      outp[(size_t)gr * 128 + j * 16 + m] = fmaxf(v[j] * rstd * gv[j] + bv[j], 0.f);
  }
}

// ---------------- host side ----------------
struct Ws {
  float *expl;
  unsigned short *btV0, *btkq0, *btW10, *btW20, *btV1, *btkq1, *btW11, *btW21, *xv, *hb;
};

static void run_stage(const float* x_f32, int R_src,
                      const int* rowptr, const int* kcnt, const int* col, int n_tgt,
                      const unsigned short* btV, const unsigned short* btkq,
                      const unsigned short* btW1, const unsigned short* btW2,
                      const float* Qw, const float* g0, const float* b0,
                      const float* g1, const float* b1,
                      float* out, const Ws& ws, hipStream_t stream)
{
  // ABLATION #3 (this round only): gemm_xvl and mfma_mlp_ln launched 3x each.
  // Both are idempotent (deterministic pure functions of their inputs; all copies
  // write identical values). mlp copies complete before the next stage's gemm reads
  // out. dur delta vs round 2 = 2x(gemm1+mlp1+gemm2+mlp2) + ~8 launch gaps -- the
  // last unmeasured block in the budget.
  gemm_xvl<<<(R_src + 1 + 63) / 64, 256, 0, stream>>>(x_f32, btV, btkq, ws.xv, ws.expl, R_src);
  gemm_xvl<<<(R_src + 1 + 63) / 64, 256, 0, stream>>>(x_f32, btV, btkq, ws.xv, ws.expl, R_src);
  gemm_xvl<<<(R_src + 1 + 63) / 64, 256, 0, stream>>>(x_f32, btV, btkq, ws.xv, ws.expl, R_src);
  agg_kernel<<<(n_tgt + 3) / 4, 256, 0, stream>>>(rowptr, kcnt, col, ws.expl, ws.xv,
                                                  Qw, g0, b0, ws.hb, n_tgt);
  mfma_mlp_ln<<<(n_tgt + 63) / 64, 256, 0, stream>>>(ws.hb, btW1, btW2, g1, b1, out, n_tgt);
  mfma_mlp_ln<<<(n_tgt + 63) / 64, 256, 0, stream>>>(ws.hb, btW1, btW2, g1, b1, out, n_tgt);
  mfma_mlp_ln<<<(n_tgt + 63) / 64, 256, 0, stream>>>(ws.hb, btW1, btW2, g1, b1, out, n_tgt);
}

extern "C" void kernel_launch(void* const* d_in, const int* in_sizes, int n_in,
                              void* d_out, int out_size, void* d_ws, size_t ws_size,
                              hipStream_t stream)
{
  const float* x0        = (const float*)d_in[0];
  const int*   node_idx  = (const int*)d_in[1];
  const int*   hedge_idx = (const int*)d_in[2];
  const float* v2e_K = (const float*)d_in[5];
  const float* v2e_Q = (const float*)d_in[6];
  const float* v2e_V = (const float*)d_in[7];
  const float* v2e_g0 = (const float*)d_in[8];
  const float* v2e_b0 = (const float*)d_in[9];
  const float* v2e_W1 = (const float*)d_in[10];
  const float* v2e_W2 = (const float*)d_in[11];
  const float* v2e_g1 = (const float*)d_in[12];
  const float* v2e_b1 = (const float*)d_in[13];
  const float* e2v_K = (const float*)d_in[14];
  const float* e2v_Q = (const float*)d_in[15];
  const float* e2v_V = (const float*)d_in[16];
  const float* e2v_g0 = (const float*)d_in[17];
  const float* e2v_b0 = (const float*)d_in[18];
  const float* e2v_W1 = (const float*)d_in[19];
  const float* e2v_W2 = (const float*)d_in[20];
  const float* e2v_g1 = (const float*)d_in[21];
  const float* e2v_b1 = (const float*)d_in[22];

  int N = in_sizes[0] / 128;          // 50000
  int E = in_sizes[1];                // 1000000
  int M = out_size / 128 - N;         // 20000

  float* out_x0 = (float*)d_out;
  float* out_x1 = (float*)d_out + (size_t)N * 128;

  size_t off = 0;
  char* base = (char*)d_ws;
  auto alloc = [&](size_t bytes) -> void* {
    void* p = base + off;
    off += (bytes + 255) & ~(size_t)255;
    return p;
  };
  int NB0 = (M + 255) >> 8;
  int NB1 = (N + 255) >> 8;
  int NBmax = NB1 > NB0 ? NB1 : NB0;
  size_t capP = (size_t)E + 1024 * (size_t)NBmax + 64;   // per-orientation pairs/col capacity

  Ws ws;
  ws.btV0  = (unsigned short*)alloc(16384 * 2);
  ws.btkq0 = (unsigned short*)alloc(1024 * 2);
  ws.btW10 = (unsigned short*)alloc(16384 * 2);
  ws.btW20 = (unsigned short*)alloc(16384 * 2);
  ws.btV1  = (unsigned short*)alloc(16384 * 2);
  ws.btkq1 = (unsigned short*)alloc(1024 * 2);
  ws.btW11 = (unsigned short*)alloc(16384 * 2);
  ws.btW21 = (unsigned short*)alloc(16384 * 2);
  ws.expl  = (float*)alloc(((size_t)N + 1) * 4 * 4);
  // big region: CSR scratch aliases {xv,hb}, both dead during CSR build
  size_t uoff = off;
  ws.xv    = (unsigned short*)alloc(((size_t)N + 1) * 128 * 2);   // 12.85 MB
  ws.hb    = (unsigned short*)alloc((size_t)N * 128 * 2);         // 12.8 MB
  int* pairs0  = (int*)(base + uoff);                             // capP ints
  int* pairs1  = pairs0 + capP;                                   // capP ints
  int* counts0 = pairs1 + capP;
  int* counts1 = counts0 + 256 * CSR_P;
  int* blkoff0 = counts1 + 256 * CSR_P;
  int* blkoff1 = blkoff0 + 256 * CSR_P;
  int* btot0   = blkoff1 + 256 * CSR_P;
  int* btot1   = btot0 + 256;
  int* base0   = btot1 + 256;
  int* base1   = base0 + 256;
  int* cursors = base1 + 256;
  int* rowptr0 = (int*)alloc((size_t)M * 4);
  int* kcnt0   = (int*)alloc((size_t)M * 4);
  int* col0    = (int*)alloc(capP * 4);
  int* rowptr1 = (int*)alloc((size_t)N * 4);
  int* kcnt1   = (int*)alloc((size_t)N * 4);
  int* col1    = (int*)alloc(capP * 4);
  (void)ws_size; (void)n_in;

  // merged weight prep + bucket histograms (all input-only)
  prephist_kernel<<<dim3(CSR_P + 194, 2), 256, 0, stream>>>(
      hedge_idx, NB0, node_idx, NB1, E, counts0, counts1,
      v2e_K, v2e_Q, v2e_V, v2e_W1, v2e_W2,
      e2v_K, e2v_Q, e2v_V, e2v_W1, e2v_W2,
      ws.btV0, ws.btkq0, ws.btW10, ws.btW20,
      ws.btV1, ws.btkq1, ws.btW11, ws.btW21, cursors);

  bscan_kernel<<<NB0 + NB1, 256, 0, stream>>>(counts0, NB0, counts1,
                                              blkoff0, blkoff1, btot0, btot1,
                                              base0, base1, cursors);
  scatter2_kernel<<<dim3(CSR_P, 2), 256, 0, stream>>>(
      hedge_idx, node_idx, NB0, base0, blkoff0, pairs0,
      node_idx, hedge_idx, NB1, base1, blkoff1, pairs1, E);
  build2_kernel<<<dim3(NBmax, 2), 1024, 0, stream>>>(
      base0, btot0, NB0, pairs0, M, /*dummy=*/N, rowptr0, kcnt0, col0,
      base1, btot1, NB1, pairs1, N, /*dummy=*/M, rowptr1, kcnt1, col1);

  // stage 1: vertex -> hyperedge, out = x_1
  run_stage(x0, N, rowptr0, kcnt0, col0, M,
            ws.btV0, ws.btkq0, ws.btW10, ws.btW20,
            v2e_Q, v2e_g0, v2e_b0, v2e_g1, v2e_b1,
            out_x1, ws, stream);

  // stage 2: hyperedge -> vertex, out = x_0_out
  run_stage(out_x1, M, rowptr1, kcnt1, col1, N,
            ws.btV1, ws.btkq1, ws.btW11, ws.btW21,
            e2v_Q, e2v_g0, e2v_b0, e2v_g1, e2v_b1,
            out_x0, ws, stream);
}

// Round 7
// 283.898 us; speedup vs baseline: 1.3558x; 1.3558x over previous
//
#include <hip/hip_runtime.h>
#include <math.h>

typedef __attribute__((ext_vector_type(8))) short bf16x8;
typedef __attribute__((ext_vector_type(4))) float f32x4;

#define CSR_P 256

// ---------------- bf16 helpers ----------------
__device__ __forceinline__ unsigned short f2bf(float f){
  union { float f; unsigned int u; } c; c.f = f;
  unsigned int u = c.u;
  u += 0x7fff + ((u >> 16) & 1);          // RNE
  return (unsigned short)(u >> 16);
}
__device__ __forceinline__ float bf2f(unsigned short h){
  union { unsigned int u; float f; } c; c.u = ((unsigned int)h) << 16;
  return c.f;
}

// ---------------- wave helpers ----------------
__device__ __forceinline__ float wsum64(float v){
  #pragma unroll
  for (int off = 32; off > 0; off >>= 1) v += __shfl_xor(v, off, 64);
  return v;
}

// ---------------- merged weight-prep + bucket histogram ----------------
__global__ __launch_bounds__(256) void prephist_kernel(
    const int* __restrict__ tgt0, int NB0, const int* __restrict__ tgt1, int NB1, int E,
    int* __restrict__ counts0, int* __restrict__ counts1,
    const float* __restrict__ K0, const float* __restrict__ Q0, const float* __restrict__ V0,
    const float* __restrict__ W10, const float* __restrict__ W20,
    const float* __restrict__ K1, const float* __restrict__ Q1, const float* __restrict__ V1,
    const float* __restrict__ W11, const float* __restrict__ W21,
    unsigned short* __restrict__ btV0, unsigned short* __restrict__ btkq0,
    unsigned short* __restrict__ btW10, unsigned short* __restrict__ btW20,
    unsigned short* __restrict__ btV1, unsigned short* __restrict__ btkq1,
    unsigned short* __restrict__ btW11, unsigned short* __restrict__ btW21,
    int* __restrict__ cursors){
  if (blockIdx.x >= CSR_P){
    int pb = blockIdx.x - CSR_P;
    if (pb == 0 && blockIdx.y == 0 && threadIdx.x == 0){ cursors[0] = 0; cursors[1] = 0; }
    const float *K, *Q, *V, *W1, *W2;
    unsigned short *btV, *btkq, *btW1, *btW2;
    if (blockIdx.y == 0){ K=K0; Q=Q0; V=V0; W1=W10; W2=W20; btV=btV0; btkq=btkq0; btW1=btW10; btW2=btW20; }
    else                { K=K1; Q=Q1; V=V1; W1=W11; W2=W21; btV=btV1; btkq=btkq1; btW1=btW11; btW2=btW21; }
    int i = pb * 256 + threadIdx.x;
    if (i < 512){
      int h = i >> 7, c = i & 127;
      const float* Kp = K + (size_t)h * 4096 + (size_t)c * 32;
      const float* Qp = Q + h * 32;
      float s = 0.f;
      #pragma unroll
      for (int d = 0; d < 32; ++d) s += Kp[d] * Qp[d];
      unsigned short hi = f2bf(s);
      btkq[h * 128 + c]       = hi;
      btkq[(4 + h) * 128 + c] = f2bf(s - bf2f(hi));
      return;
    }
    int j = i - 512;
    if (j < 16384){
      int n = j >> 7, k = j & 127;
      int h = n >> 5, d = n & 31;
      btV[j] = f2bf(V[(size_t)h * 4096 + (size_t)k * 32 + d]);
      return;
    }
    j -= 16384;
    if (j < 16384){
      int n = j >> 7, k = j & 127;
      btW1[j] = f2bf(W1[(size_t)k * 128 + n]);
      return;
    }
    j -= 16384;
    if (j < 16384){
      int n = j >> 7, k = j & 127;
      btW2[j] = f2bf(W2[(size_t)k * 128 + n]);
    }
    return;
  }
  // histogram role
  const int* tgt; int NB; int* counts;
  if (blockIdx.y == 0){ tgt = tgt0; NB = NB0; counts = counts0; }
  else                { tgt = tgt1; NB = NB1; counts = counts1; }
  __shared__ int hist[256];
  for (int i = threadIdx.x; i < NB; i += 256) hist[i] = 0;
  __syncthreads();
  int chunk = (E + CSR_P - 1) / CSR_P;
  int b0 = blockIdx.x * chunk, b1 = min(b0 + chunk, E);
  for (int e = b0 + threadIdx.x; e < b1; e += 256)
    atomicAdd(&hist[tgt[e] >> 8], 1);
  __syncthreads();
  for (int i = threadIdx.x; i < NB; i += 256)
    counts[i * CSR_P + blockIdx.x] = hist[i];
}

// Per-bucket scan over its 256 chunk-counts; bucket base assigned via atomic cursor.
__global__ __launch_bounds__(256) void bscan_kernel(const int* __restrict__ counts0, int NB0,
                                                    const int* __restrict__ counts1,
                                                    int* __restrict__ blkoff0, int* __restrict__ blkoff1,
                                                    int* __restrict__ btot0, int* __restrict__ btot1,
                                                    int* __restrict__ base0, int* __restrict__ base1,
                                                    int* __restrict__ cursors){
  int i = blockIdx.x;
  const int* counts; int* blkoff; int* btot; int* bbase; int* cur; int b;
  if (i < NB0){ counts = counts0; blkoff = blkoff0; btot = btot0; bbase = base0; cur = &cursors[0]; b = i; }
  else        { counts = counts1; blkoff = blkoff1; btot = btot1; bbase = base1; cur = &cursors[1]; b = i - NB0; }
  __shared__ int wtmp[5];
  int tid = threadIdx.x, lane = tid & 63, wv = tid >> 6;
  int c = counts[b * CSR_P + tid];
  int s = c;
  #pragma unroll
  for (int off = 1; off < 64; off <<= 1){
    int t = __shfl_up(s, off, 64);
    if (lane >= off) s += t;
  }
  if (lane == 63) wtmp[wv] = s;
  __syncthreads();
  if (tid == 0){
    int a0 = wtmp[0], a1 = wtmp[1], a2 = wtmp[2], a3 = wtmp[3];
    wtmp[0] = 0; wtmp[1] = a0; wtmp[2] = a0 + a1; wtmp[3] = a0 + a1 + a2;
    int total = a0 + a1 + a2 + a3;
    wtmp[4] = total;
    btot[b] = total;
    int padded = ((total + 3) & ~3) + 1024;      // room for per-row x4 padding
    bbase[b] = atomicAdd(cur, padded);           // 4-aligned (padded is x4)
  }
  __syncthreads();
  blkoff[b * CSR_P + tid] = s - c + wtmp[wv];
}

// ---------------- gemm_xvl body (shared by standalone + merged kernel) ----------------
__device__ __forceinline__ void gemm_xvl_body(unsigned short* As, unsigned short* Bs,
                                              const float* __restrict__ x,
                                              const unsigned short* __restrict__ btV,
                                              const unsigned short* __restrict__ btkq,
                                              unsigned short* __restrict__ xv,
                                              float* __restrict__ expl, int R, int bx){
  int tid = threadIdx.x;
  int row0 = bx * 64;

  #pragma unroll
  for (int i = 0; i < 16; ++i){
    int f = tid + i * 256;
    int n = f >> 5, c4 = f & 31;
    *(ushort4*)&Bs[n * 136 + c4 * 4] = *(const ushort4*)(btV + n * 128 + c4 * 4);
  }
  {
    int n = tid >> 5, c4 = tid & 31;       // 256 ushort4 = rows 128..135
    *(ushort4*)&Bs[(128 + n) * 136 + c4 * 4] = *(const ushort4*)(btkq + n * 128 + c4 * 4);
  }
  #pragma unroll
  for (int i = 0; i < 8; ++i){
    int f = tid + i * 256;
    int r = f >> 5, c4 = f & 31;
    float4 v = make_float4(0.f, 0.f, 0.f, 0.f);
    if (row0 + r < R) v = *(const float4*)(x + (size_t)(row0 + r) * 128 + c4 * 4);
    ushort4 h;
    h.x = f2bf(v.x); h.y = f2bf(v.y); h.z = f2bf(v.z); h.w = f2bf(v.w);
    *(ushort4*)&As[r * 136 + c4 * 4] = h;
  }
  __syncthreads();

  int lane = tid & 63, wv = tid >> 6;
  int m = lane & 15, quad = lane >> 4;
  f32x4 acc[9];
  #pragma unroll
  for (int j = 0; j < 9; ++j) acc[j] = (f32x4){0.f, 0.f, 0.f, 0.f};

  #pragma unroll
  for (int q = 0; q < 4; ++q){
    bf16x8 a = *(const bf16x8*)&As[(wv * 16 + m) * 136 + q * 32 + quad * 8];
    #pragma unroll
    for (int j = 0; j < 9; ++j){
      bf16x8 b = *(const bf16x8*)&Bs[(j * 16 + m) * 136 + q * 32 + quad * 8];
      acc[j] = __builtin_amdgcn_mfma_f32_16x16x32_bf16(a, b, acc[j], 0, 0, 0);
    }
  }

  #pragma unroll
  for (int j = 0; j < 8; ++j){
    int colc = j * 16 + m;
    #pragma unroll
    for (int r = 0; r < 4; ++r){
      int gr = row0 + wv * 16 + quad * 4 + r;
      if (gr <= R) xv[(size_t)gr * 128 + colc] = f2bf(acc[j][r]);   // row R: acc==0
    }
  }
  #pragma unroll
  for (int r = 0; r < 4; ++r){
    int gr = row0 + wv * 16 + quad * 4 + r;
    float lg = acc[8][r] + __shfl_xor(acc[8][r], 4, 64);   // hi + lo (lanes m<4 valid)
    if (m < 4 && gr <= R)
      expl[(size_t)gr * 4 + m] = (gr == R) ? 0.f : __expf(lg);
  }
}

// ---------------- standalone gemm_xvl (stage 2) ----------------
__global__ __launch_bounds__(256) void gemm_xvl(const float* __restrict__ x,
                                                const unsigned short* __restrict__ btV,
                                                const unsigned short* __restrict__ btkq,
                                                unsigned short* __restrict__ xv,
                                                float* __restrict__ expl, int R){
  __shared__ unsigned short As[64 * 136];
  __shared__ unsigned short Bs[144 * 136];   // rows 136..143 uninit: pollute only unused cols
  gemm_xvl_body(As, Bs, x, btV, btkq, xv, expl, R, blockIdx.x);
}

// ---------------- merged scatter (both orientations) + stage-1 gemm_xvl ----------------
// Legal because xv/expl do not alias the CSR pairs scratch: scatter writes pairs,
// gemm writes xv/expl -- disjoint. gemm1 depends only on prephist outputs (btV0/btkq0)
// and x0; scatter depends on bscan -- both satisfied here. Overlaps gemm's MFMA/stream
// work with scatter's atomic-bound work; saves one launch gap. (Verified correct in
// round 5; round-5's regression was the agg channel-split, reverted.)
__global__ __launch_bounds__(256) void scatgemm_kernel(
    const int* __restrict__ tgt0, const int* __restrict__ src0, int NB0,
    const int* __restrict__ base0, const int* __restrict__ blkoff0, int* __restrict__ pairs0,
    const int* __restrict__ tgt1, const int* __restrict__ src1, int NB1,
    const int* __restrict__ base1, const int* __restrict__ blkoff1, int* __restrict__ pairs1,
    int E,
    const float* __restrict__ x, const unsigned short* __restrict__ btV,
    const unsigned short* __restrict__ btkq,
    unsigned short* __restrict__ xv, float* __restrict__ expl, int R){
  __shared__ unsigned short As[64 * 136];
  __shared__ unsigned short Bs[144 * 136];
  if (blockIdx.x < 2 * CSR_P){
    // scatter role
    int y = blockIdx.x >> 8;          // orientation
    int bx = blockIdx.x & 255;        // chunk
    const int *tgt, *src, *bbase, *boff; int NB; int* pairs;
    if (y == 0){ tgt=tgt0; src=src0; bbase=base0; boff=blkoff0; NB=NB0; pairs=pairs0; }
    else       { tgt=tgt1; src=src1; bbase=base1; boff=blkoff1; NB=NB1; pairs=pairs1; }
    int* cur = (int*)As;              // LDS overlay
    for (int i = threadIdx.x; i < NB; i += 256)
      cur[i] = bbase[i] + boff[i * CSR_P + bx];
    __syncthreads();
    int chunk = (E + CSR_P - 1) / CSR_P;
    int b0 = bx * chunk, b1 = min(b0 + chunk, E);
    for (int e = b0 + threadIdx.x; e < b1; e += 256){
      int t = tgt[e];
      int pos = atomicAdd(&cur[t >> 8], 1);
      pairs[pos] = ((t & 255) << 24) | src[e];     // src < 2^24
    }
    return;
  }
  gemm_xvl_body(As, Bs, x, btV, btkq, xv, expl, R, blockIdx.x - 2 * CSR_P);
}

// Within each 256-target bucket: counting-scatter keyed by (tgt, src>>13) so each
// row's cols come out sorted by source tile.
__global__ __launch_bounds__(1024) void build2_kernel(
    const int* __restrict__ base0, const int* __restrict__ btot0, int NB0,
    const int* __restrict__ pairs0, int n0, int d0,
    int* __restrict__ rp0, int* __restrict__ kc0, int* __restrict__ col0,
    const int* __restrict__ base1, const int* __restrict__ btot1, int NB1,
    const int* __restrict__ pairs1, int n1, int d1,
    int* __restrict__ rp1, int* __restrict__ kc1, int* __restrict__ col1){
  int b = blockIdx.x;
  const int *bbase, *bt; const int* pairs; int n_tgt, dummy;
  int *rowptr, *kcnt, *col;
  if (blockIdx.y == 0){
    if (b >= NB0) return;
    bbase=base0; bt=btot0; pairs=pairs0; n_tgt=n0; dummy=d0; rowptr=rp0; kcnt=kc0; col=col0;
  } else {
    if (b >= NB1) return;
    bbase=base1; bt=btot1; pairs=pairs1; n_tgt=n1; dummy=d1; rowptr=rp1; kcnt=kc1; col=col1;
  }
  __shared__ int hist2[2048];   // per-(tgt, tile) counts, tile = src >> 13
  __shared__ int cur2[2048];    // running scatter cursors per (tgt, tile)
  __shared__ int hist[256];     // per-tgt totals
  __shared__ int excl[256];     // per-tgt exclusive (padded) offsets
  int tid = threadIdx.x;
  int start = bbase[b];              // 4-aligned by construction
  int end   = start + bt[b];
  for (int i = tid; i < 2048; i += 1024) hist2[i] = 0;
  __syncthreads();
  for (int e = start + tid; e < end; e += 1024){
    int p = pairs[e];
    atomicAdd(&hist2[(((p >> 24) & 255) << 3) | ((p & 0xFFFFFF) >> 13)], 1);
  }
  __syncthreads();
  if (tid < 256){
    int run = 0;
    #pragma unroll
    for (int t = 0; t < 8; ++t){ cur2[tid * 8 + t] = run; run += hist2[tid * 8 + t]; }
    hist[tid] = run;
  }
  __syncthreads();
  if (tid < 64){
    int lane = tid;
    int p0 = (hist[4 * lane]     + 3) & ~3;
    int p1 = (hist[4 * lane + 1] + 3) & ~3;
    int p2 = (hist[4 * lane + 2] + 3) & ~3;
    int p3 = (hist[4 * lane + 3] + 3) & ~3;
    int tsum = p0 + p1 + p2 + p3;
    int s = tsum;
    #pragma unroll
    for (int off = 1; off < 64; off <<= 1){
      int t = __shfl_up(s, off, 64);
      if (lane >= off) s += t;
    }
    int e0 = s - tsum;
    excl[4 * lane]     = e0;
    excl[4 * lane + 1] = e0 + p0;
    excl[4 * lane + 2] = e0 + p0 + p1;
    excl[4 * lane + 3] = e0 + p0 + p1 + p2;
  }
  __syncthreads();
  int t0 = b << 8;
  int valid = min(256, n_tgt - t0);
  if (tid < 256){
    int e0 = excl[tid];
    #pragma unroll
    for (int t = 0; t < 8; ++t) cur2[tid * 8 + t] += e0;
  }
  for (int i = tid; i < valid; i += 1024){
    rowptr[t0 + i] = start + excl[i];
    kcnt[t0 + i]   = (hist[i] + 3) & ~3;
  }
  __syncthreads();
  for (int e = start + tid; e < end; e += 1024){
    int p = pairs[e];
    int s = p & 0xFFFFFF;
    int pos = atomicAdd(&cur2[(((p >> 24) & 255) << 3) | (s >> 13)], 1);
    col[start + pos] = s;
  }
  __syncthreads();
  for (int i = tid; i < valid; i += 1024){
    int hc = hist[i], pc = (hc + 3) & ~3;
    int base = start + excl[i];
    for (int j = hc; j < pc; ++j) col[base + j] = dummy;
  }
}

// ---------------- softmax-aggregate + (+Qw) + LN0 : one wave per target ----------------
__global__ __launch_bounds__(256) void agg_kernel(const int* __restrict__ rowptr,
                                                  const int* __restrict__ kcnt,
                                                  const int* __restrict__ col,
                                                  const float* __restrict__ expl,
                                                  const unsigned short* __restrict__ xV,
                                                  const float* __restrict__ qvec,
                                                  const float* __restrict__ g0,
                                                  const float* __restrict__ b0,
                                                  unsigned short* __restrict__ hb_out,
                                                  int n_tgt){
  int wv_id = __builtin_amdgcn_readfirstlane(threadIdx.x >> 6);
  int wid = (blockIdx.x << 2) + wv_id;
  if (wid >= n_tgt) return;
  int lane = threadIdx.x & 63;
  int half = lane >> 5;                 // which edge of the pair this lane serves
  int c    = lane & 31;                 // channel block: channels 4c .. 4c+3
  unsigned hh = (unsigned)(c >> 3);     // head of this channel block
  int beg = rowptr[wid];          // scalar load
  int k   = kcnt[wid];            // scalar load

  const uint2* xv64 = (const uint2*)xV;
  float acc0 = 0.f, acc1 = 0.f, acc2 = 0.f, acc3 = 0.f, sumw = 0.f;
  #pragma unroll 2
  for (int e = 0; e < k; e += 4){
    int4 cc = *(const int4*)(col + beg + e);      // s_load_dwordx4 (uniform address)
    #pragma unroll
    for (int p = 0; p < 2; ++p){
      int sA = p ? cc.z : cc.x;
      int sB = p ? cc.w : cc.y;
      int se = half ? sB : sA;                    // per-lane select (v_cndmask)
      float a  = expl[((unsigned)se << 2) + hh];  // 1 dword / edge-pair-half
      uint2 v  = xv64[((unsigned)se << 5) + (unsigned)c];  // 8B: 4 channels
      union { unsigned u; float f; } t0, t1, t2, t3;
      t0.u = v.x << 16;          t1.u = v.x & 0xffff0000u;
      t2.u = v.y << 16;          t3.u = v.y & 0xffff0000u;
      sumw += a;
      acc0 += a * t0.f;  acc1 += a * t1.f;
      acc2 += a * t2.f;  acc3 += a * t3.f;
    }
  }
  // fold the two halves (each processed every other edge)
  sumw += __shfl_xor(sumw, 32, 64);
  acc0 += __shfl_xor(acc0, 32, 64);
  acc1 += __shfl_xor(acc1, 32, 64);
  acc2 += __shfl_xor(acc2, 32, 64);
  acc3 += __shfl_xor(acc3, 32, 64);

  float inv = (sumw > 0.f) ? 1.f / sumw : 0.f;
  acc0 *= inv; acc1 *= inv; acc2 *= inv; acc3 *= inv;

  float4 q4 = *(const float4*)(qvec + 4 * c);
  acc0 += q4.x; acc1 += q4.y; acc2 += q4.z; acc3 += q4.w;

  // every channel is present in both halves -> divide by 256, not 128
  float mean = wsum64(acc0 + acc1 + acc2 + acc3) * (1.f / 256.f);
  float d0 = acc0 - mean, d1 = acc1 - mean, d2 = acc2 - mean, d3 = acc3 - mean;
  float var = wsum64(d0 * d0 + d1 * d1 + d2 * d2 + d3 * d3) * (1.f / 256.f);
  float rstd = rsqrtf(var + 1e-5f);
  float4 g4 = *(const float4*)(g0 + 4 * c);
  float4 b4 = *(const float4*)(b0 + 4 * c);
  float o0 = d0 * rstd * g4.x + b4.x;
  float o1 = d1 * rstd * g4.y + b4.y;
  float o2 = d2 * rstd * g4.z + b4.z;
  float o3 = d3 * rstd * g4.w + b4.w;
  if (half == 0){
    uint2 pk;
    pk.x = ((unsigned)f2bf(o1) << 16) | (unsigned)f2bf(o0);
    pk.y = ((unsigned)f2bf(o3) << 16) | (unsigned)f2bf(o2);
    *(uint2*)(hb_out + 128 * (size_t)wid + 4 * c) = pk;
  }
}

// ---------------- fused MLP + LN1: out = relu(LN(A + relu(relu(A@W1)@W2))) ------------
__global__ __launch_bounds__(256) void mfma_mlp_ln(const unsigned short* __restrict__ A,
                                                   const unsigned short* __restrict__ Bt1,
                                                   const unsigned short* __restrict__ Bt2,
                                                   const float* __restrict__ g,
                                                   const float* __restrict__ b,
                                                   float* __restrict__ outp, int R){
  __shared__ unsigned short As[64 * 136];
  __shared__ unsigned short Bs[128 * 136];
  int tid = threadIdx.x;
  int row0 = blockIdx.x * 64;

  #pragma unroll
  for (int i = 0; i < 16; ++i){
    int f = tid + i * 256;
    int n = f >> 5, c4 = f & 31;
    *(ushort4*)&Bs[n * 136 + c4 * 4] = *(const ushort4*)(Bt1 + n * 128 + c4 * 4);
  }
  #pragma unroll
  for (int i = 0; i < 8; ++i){
    int f = tid + i * 256;
    int r = f >> 5, c4 = f & 31;
    ushort4 v = make_ushort4(0, 0, 0, 0);
    if (row0 + r < R) v = *(const ushort4*)(A + (size_t)(row0 + r) * 128 + c4 * 4);
    *(ushort4*)&As[r * 136 + c4 * 4] = v;
  }
  __syncthreads();

  int lane = tid & 63, wv = tid >> 6;
  int m = lane & 15, quad = lane >> 4;
  f32x4 acc[8];
  #pragma unroll
  for (int j = 0; j < 8; ++j) acc[j] = (f32x4){0.f, 0.f, 0.f, 0.f};

  // t = relu(A @ W1)
  #pragma unroll
  for (int q = 0; q < 4; ++q){
    bf16x8 a = *(const bf16x8*)&As[(wv * 16 + m) * 136 + q * 32 + quad * 8];
    #pragma unroll
    for (int j = 0; j < 8; ++j){
      bf16x8 b8 = *(const bf16x8*)&Bs[(j * 16 + m) * 136 + q * 32 + quad * 8];
      acc[j] = __builtin_amdgcn_mfma_f32_16x16x32_bf16(a, b8, acc[j], 0, 0, 0);
    }
  }

  // pre-read residual before overwrite
  float res[4][8];
  #pragma unroll
  for (int r = 0; r < 4; ++r)
    #pragma unroll
    for (int j = 0; j < 8; ++j)
      res[r][j] = bf2f(As[(wv * 16 + quad * 4 + r) * 136 + j * 16 + m]);
  __syncthreads();

  // t -> As (bf16), W2^T -> Bs
  #pragma unroll
  for (int j = 0; j < 8; ++j){
    #pragma unroll
    for (int r = 0; r < 4; ++r)
      As[(wv * 16 + quad * 4 + r) * 136 + j * 16 + m] = f2bf(fmaxf(acc[j][r], 0.f));
  }
  #pragma unroll
  for (int i = 0; i < 16; ++i){
    int f = tid + i * 256;
    int n = f >> 5, c4 = f & 31;
    *(ushort4*)&Bs[n * 136 + c4 * 4] = *(const ushort4*)(Bt2 + n * 128 + c4 * 4);
  }
  __syncthreads();

  // m2 = t @ W2
  #pragma unroll
  for (int j = 0; j < 8; ++j) acc[j] = (f32x4){0.f, 0.f, 0.f, 0.f};
  #pragma unroll
  for (int q = 0; q < 4; ++q){
    bf16x8 a = *(const bf16x8*)&As[(wv * 16 + m) * 136 + q * 32 + quad * 8];
    #pragma unroll
    for (int j = 0; j < 8; ++j){
      bf16x8 b8 = *(const bf16x8*)&Bs[(j * 16 + m) * 136 + q * 32 + quad * 8];
      acc[j] = __builtin_amdgcn_mfma_f32_16x16x32_bf16(a, b8, acc[j], 0, 0, 0);
    }
  }

  float gv[8], bv[8];
  #pragma unroll
  for (int j = 0; j < 8; ++j){ gv[j] = g[j * 16 + m]; bv[j] = b[j * 16 + m]; }

  #pragma unroll
  for (int r = 0; r < 4; ++r){
    int gr = row0 + wv * 16 + quad * 4 + r;
    if (gr >= R) continue;
    float v[8];
    float s = 0.f;
    #pragma unroll
    for (int j = 0; j < 8; ++j){
      float mm = fmaxf(acc[j][r], 0.f);
      v[j] = res[r][j] + mm;
      s += v[j];
    }
    s += __shfl_xor(s, 1, 64); s += __shfl_xor(s, 2, 64);
    s += __shfl_xor(s, 4, 64); s += __shfl_xor(s, 8, 64);
    float mean = s * (1.f / 128.f);
    float s2 = 0.f;
    #pragma unroll
    for (int j = 0; j < 8; ++j){ v[j] -= mean; s2 += v[j] * v[j]; }
    s2 += __shfl_xor(s2, 1, 64); s2 += __shfl_xor(s2, 2, 64);
    s2 += __shfl_xor(s2, 4, 64); s2 += __shfl_xor(s2, 8, 64);
    float rstd = rsqrtf(s2 * (1.f / 128.f) + 1e-5f);
    #pragma unroll
    for (int j = 0; j < 8; ++j)
      outp[(size_t)gr * 128 + j * 16 + m] = fmaxf(v[j] * rstd * gv[j] + bv[j], 0.f);
  }
}

// ---------------- host side ----------------
struct Ws {
  float *expl;
  unsigned short *btV0, *btkq0, *btW10, *btW20, *btV1, *btkq1, *btW11, *btW21, *xv, *hb;
};

extern "C" void kernel_launch(void* const* d_in, const int* in_sizes, int n_in,
                              void* d_out, int out_size, void* d_ws, size_t ws_size,
                              hipStream_t stream)
{
  const float* x0        = (const float*)d_in[0];
  const int*   node_idx  = (const int*)d_in[1];
  const int*   hedge_idx = (const int*)d_in[2];
  const float* v2e_K = (const float*)d_in[5];
  const float* v2e_Q = (const float*)d_in[6];
  const float* v2e_V = (const float*)d_in[7];
  const float* v2e_g0 = (const float*)d_in[8];
  const float* v2e_b0 = (const float*)d_in[9];
  const float* v2e_W1 = (const float*)d_in[10];
  const float* v2e_W2 = (const float*)d_in[11];
  const float* v2e_g1 = (const float*)d_in[12];
  const float* v2e_b1 = (const float*)d_in[13];
  const float* e2v_K = (const float*)d_in[14];
  const float* e2v_Q = (const float*)d_in[15];
  const float* e2v_V = (const float*)d_in[16];
  const float* e2v_g0 = (const float*)d_in[17];
  const float* e2v_b0 = (const float*)d_in[18];
  const float* e2v_W1 = (const float*)d_in[19];
  const float* e2v_W2 = (const float*)d_in[20];
  const float* e2v_g1 = (const float*)d_in[21];
  const float* e2v_b1 = (const float*)d_in[22];

  int N = in_sizes[0] / 128;          // 50000
  int E = in_sizes[1];                // 1000000
  int M = out_size / 128 - N;         // 20000

  float* out_x0 = (float*)d_out;
  float* out_x1 = (float*)d_out + (size_t)N * 128;

  size_t off = 0;
  char* base = (char*)d_ws;
  auto alloc = [&](size_t bytes) -> void* {
    void* p = base + off;
    off += (bytes + 255) & ~(size_t)255;
    return p;
  };
  int NB0 = (M + 255) >> 8;
  int NB1 = (N + 255) >> 8;
  int NBmax = NB1 > NB0 ? NB1 : NB0;
  size_t capP = (size_t)E + 1024 * (size_t)NBmax + 64;   // per-orientation pairs/col capacity

  Ws ws;
  ws.btV0  = (unsigned short*)alloc(16384 * 2);
  ws.btkq0 = (unsigned short*)alloc(1024 * 2);
  ws.btW10 = (unsigned short*)alloc(16384 * 2);
  ws.btW20 = (unsigned short*)alloc(16384 * 2);
  ws.btV1  = (unsigned short*)alloc(16384 * 2);
  ws.btkq1 = (unsigned short*)alloc(1024 * 2);
  ws.btW11 = (unsigned short*)alloc(16384 * 2);
  ws.btW21 = (unsigned short*)alloc(16384 * 2);
  ws.expl  = (float*)alloc(((size_t)N + 1) * 4 * 4);
  // xv/expl do NOT alias the CSR pairs scratch: required for the scatgemm merge
  // (scatter writes pairs while gemm writes xv/expl concurrently).
  ws.xv    = (unsigned short*)alloc(((size_t)N + 1) * 128 * 2);   // 12.85 MB
  ws.hb    = (unsigned short*)alloc((size_t)N * 128 * 2);         // 12.8 MB
  int* pairs0  = (int*)alloc(capP * 4);
  int* pairs1  = (int*)alloc(capP * 4);
  int* counts0 = (int*)alloc(256 * CSR_P * 4);
  int* counts1 = (int*)alloc(256 * CSR_P * 4);
  int* blkoff0 = (int*)alloc(256 * CSR_P * 4);
  int* blkoff1 = (int*)alloc(256 * CSR_P * 4);
  int* btot0   = (int*)alloc(256 * 4);
  int* btot1   = (int*)alloc(256 * 4);
  int* base0   = (int*)alloc(256 * 4);
  int* base1   = (int*)alloc(256 * 4);
  int* cursors = (int*)alloc(256 * 4);
  int* rowptr0 = (int*)alloc((size_t)M * 4);
  int* kcnt0   = (int*)alloc((size_t)M * 4);
  int* col0    = (int*)alloc(capP * 4);
  int* rowptr1 = (int*)alloc((size_t)N * 4);
  int* kcnt1   = (int*)alloc((size_t)N * 4);
  int* col1    = (int*)alloc(capP * 4);
  (void)ws_size; (void)n_in;

  // merged weight prep + bucket histograms (all input-only)
  prephist_kernel<<<dim3(CSR_P + 194, 2), 256, 0, stream>>>(
      hedge_idx, NB0, node_idx, NB1, E, counts0, counts1,
      v2e_K, v2e_Q, v2e_V, v2e_W1, v2e_W2,
      e2v_K, e2v_Q, e2v_V, e2v_W1, e2v_W2,
      ws.btV0, ws.btkq0, ws.btW10, ws.btW20,
      ws.btV1, ws.btkq1, ws.btW11, ws.btW21, cursors);

  bscan_kernel<<<NB0 + NB1, 256, 0, stream>>>(counts0, NB0, counts1,
                                              blkoff0, blkoff1, btot0, btot1,
                                              base0, base1, cursors);

  // scatter (both orientations) + stage-1 gemm_xvl, one launch
  int G1 = (N + 1 + 63) / 64;
  scatgemm_kernel<<<2 * CSR_P + G1, 256, 0, stream>>>(
      hedge_idx, node_idx, NB0, base0, blkoff0, pairs0,
      node_idx, hedge_idx, NB1, base1, blkoff1, pairs1, E,
      x0, ws.btV0, ws.btkq0, ws.xv, ws.expl, N);

  build2_kernel<<<dim3(NBmax, 2), 1024, 0, stream>>>(
      base0, btot0, NB0, pairs0, M, /*dummy=*/N, rowptr0, kcnt0, col0,
      base1, btot1, NB1, pairs1, N, /*dummy=*/M, rowptr1, kcnt1, col1);

  // stage 1: vertex -> hyperedge, out = x_1
  agg_kernel<<<(M + 3) / 4, 256, 0, stream>>>(rowptr0, kcnt0, col0, ws.expl, ws.xv,
                                              v2e_Q, v2e_g0, v2e_b0, ws.hb, M);
  mfma_mlp_ln<<<(M + 63) / 64, 256, 0, stream>>>(ws.hb, ws.btW10, ws.btW20,
                                                 v2e_g1, v2e_b1, out_x1, M);

  // stage 2: hyperedge -> vertex, out = x_0_out
  gemm_xvl<<<(M + 1 + 63) / 64, 256, 0, stream>>>(out_x1, ws.btV1, ws.btkq1,
                                                  ws.xv, ws.expl, M);
  agg_kernel<<<(N + 3) / 4, 256, 0, stream>>>(rowptr1, kcnt1, col1, ws.expl, ws.xv,
                                              e2v_Q, e2v_g0, e2v_b0, ws.hb, N);
  mfma_mlp_ln<<<(N + 63) / 64, 256, 0, stream>>>(ws.hb, ws.btW11, ws.btW21,
                                                 e2v_g1, e2v_b1, out_x0, N);
}